// Round 13
// baseline (533.980 us; speedup 1.0000x reference)
//
#include <hip/hip_runtime.h>
#include <hip/hip_bf16.h>

#define Bn 128
#define Tn 512
#define En 100
#define G4 256   // 4*HD
#define Hn 128
#define Kn 12

typedef short bf16x8 __attribute__((ext_vector_type(8)));
typedef float f32x4 __attribute__((ext_vector_type(4)));

// Raw barrier: lgkmcnt(0) + s_barrier, no vmcnt drain (prefetch survives).
__device__ __forceinline__ void wg_barrier() {
  asm volatile("s_waitcnt lgkmcnt(0)" ::: "memory");
  __builtin_amdgcn_s_barrier();
  asm volatile("" ::: "memory");
}

__device__ __forceinline__ float exp2_hw(float x) {
  float r; asm("v_exp_f32 %0, %1" : "=v"(r) : "v"(x)); return r;
}
__device__ __forceinline__ float rcp_hw(float x) {
  float r; asm("v_rcp_f32 %0, %1" : "=v"(r) : "v"(x)); return r;
}
__device__ __forceinline__ float fast_sigm(float x) {
  return rcp_hw(1.0f + exp2_hw(x * -1.4426950408889634f));
}
__device__ __forceinline__ float fast_tanh(float x) {
  return 1.0f - 2.0f * rcp_hw(1.0f + exp2_hw(x * 2.8853900817779268f));
}
// pack 2 floats -> 2 bf16 (RNE) in one u32
__device__ __forceinline__ unsigned int pk2bf(float a, float b) {
  unsigned int ua = __float_as_uint(a); ua += 0x7FFFu + ((ua >> 16) & 1u);
  unsigned int ub = __float_as_uint(b); ub += 0x7FFFu + ((ub >> 16) & 1u);
  return (ua >> 16) | (ub & 0xFFFF0000u);
}
__device__ __forceinline__ unsigned short f2bf(float a) {
  unsigned int ua = __float_as_uint(a); ua += 0x7FFFu + ((ua >> 16) & 1u);
  return (unsigned short)(ua >> 16);
}

// ---------------- K1: proj via MFMA bf16 (validated r10) ------------------
__global__ __launch_bounds__(256) void proj_kernel(
    const int* __restrict__ sent, const float* __restrict__ embed,
    const float* __restrict__ WihF, const float* __restrict__ WihB,
    const float* __restrict__ bihF, const float* __restrict__ bhhF,
    const float* __restrict__ bihB, const float* __restrict__ bhhB,
    float* __restrict__ xgF, float* __restrict__ xgB, int dirSel) {
  __shared__ __align__(16) unsigned short embS[64][128];
  __shared__ __align__(16) unsigned short wS[128][128];
  __shared__ float bias_s[128];
  const int tid = threadIdx.x;
  const int nhalf = blockIdx.y;
  const int dir = (dirSel >= 0) ? dirSel : (int)blockIdx.z;
  const float* Wih = dir ? WihB : WihF;
  const float* bih = dir ? bihB : bihF;
  const float* bhh = dir ? bhhB : bhhF;
  float* xg = dir ? xgB : xgF;
  const int n0 = blockIdx.x * 64;
  const int g0 = nhalf * 128;
  {
    const int t = tid >> 2, q = tid & 3;
    const int row = sent[n0 + t];
    const float* er = embed + (size_t)row * En;
    for (int c = q; c < 16; c += 4) {
      uint4 wv;
      if (c < 12) {
        const float4 f0 = *(const float4*)(er + 8 * c);
        const float4 f1 = *(const float4*)(er + 8 * c + 4);
        wv = make_uint4(pk2bf(f0.x, f0.y), pk2bf(f0.z, f0.w),
                        pk2bf(f1.x, f1.y), pk2bf(f1.z, f1.w));
      } else if (c == 12) {
        float f[8];
#pragma unroll
        for (int j = 0; j < 8; ++j) { const int e = 96 + j; f[j] = (e < En) ? er[e] : 0.f; }
        wv = make_uint4(pk2bf(f[0], f[1]), pk2bf(f[2], f[3]),
                        pk2bf(f[4], f[5]), pk2bf(f[6], f[7]));
      } else {
        wv = make_uint4(0, 0, 0, 0);
      }
      *(uint4*)&embS[t][8 * (c ^ (t & 7))] = wv;
    }
  }
  {
    const int r = tid >> 1, q = tid & 1;
    const float* wr = Wih + (size_t)(g0 + r) * En;
    for (int c = q; c < 16; c += 2) {
      uint4 wv;
      if (c < 12) {
        const float4 f0 = *(const float4*)(wr + 8 * c);
        const float4 f1 = *(const float4*)(wr + 8 * c + 4);
        wv = make_uint4(pk2bf(f0.x, f0.y), pk2bf(f0.z, f0.w),
                        pk2bf(f1.x, f1.y), pk2bf(f1.z, f1.w));
      } else if (c == 12) {
        float f[8];
#pragma unroll
        for (int j = 0; j < 8; ++j) { const int e = 96 + j; f[j] = (e < En) ? wr[e] : 0.f; }
        wv = make_uint4(pk2bf(f[0], f[1]), pk2bf(f[2], f[3]),
                        pk2bf(f[4], f[5]), pk2bf(f[6], f[7]));
      } else {
        wv = make_uint4(0, 0, 0, 0);
      }
      *(uint4*)&wS[r][8 * (c ^ (r & 7))] = wv;
    }
  }
  if (tid < 128) bias_s[tid] = bih[g0 + tid] + bhh[g0 + tid];
  __syncthreads();
  const int m = tid >> 6;
  const int lane = tid & 63;
  const int lr = lane & 15;
  const int lq = lane >> 4;
  const int t = 16 * m + lr;
  f32x4 acc[8] = {};
#pragma unroll
  for (int ks = 0; ks < 4; ++ks) {
    const int cs = 4 * ks + lq;
    const bf16x8 af = *(const bf16x8*)&embS[t][8 * (cs ^ (lr & 7))];
#pragma unroll
    for (int nt = 0; nt < 8; ++nt) {
      const int g = 16 * nt + lr;
      const bf16x8 bf = *(const bf16x8*)&wS[g][8 * (cs ^ (lr & 7))];
      acc[nt] = __builtin_amdgcn_mfma_f32_16x16x32_bf16(af, bf, acc[nt], 0, 0, 0);
    }
  }
  float* xbase = xg + (size_t)(n0 + 16 * m) * G4 + g0;
#pragma unroll
  for (int nt = 0; nt < 8; ++nt) {
    const int g = 16 * nt + lr;
    const float bv = bias_s[g];
#pragma unroll
    for (int j = 0; j < 4; ++j) {
      const int tok = 4 * lq + j;
      xbase[(size_t)tok * G4 + g] = acc[nt][j] + bv;
    }
  }
}

// ---------------- K2: LSTM recurrence via MFMA --------------------------
// W_hh shared across batch => each step is H_t[16x64] @ W^T[64x256] per
// block (16 blocks: 8 batch-groups x 2 dirs). Wave w owns tiles
// nt={w,4+w,8+w,12+w} = all 4 gate types of units 16w+0..15, so the
// c/h update is lane-local (C-layout row=4*(lane>>4)+j = batch, col=lane&15
// = unit within group; same mapping validated in proj). h round-trips
// through a 2KB dbuf bf16 LDS tile (1 barrier/step); c stays f32 in regs;
// feats written f32. W B-frags hoisted to regs ((256,1) lifts VGPR cap).
__global__ __launch_bounds__(256, 1) void lstm_mfma_kernel(
    const float* __restrict__ xgF, const float* __restrict__ xgB,
    const float* __restrict__ WhhF, const float* __restrict__ WhhB,
    const float* __restrict__ h0, const float* __restrict__ c0,
    float* __restrict__ feats, int dirSel) {
  __shared__ __align__(16) unsigned short wS[256 * 64];    // bf16, swizzled
  __shared__ __align__(16) unsigned short hS[2][16 * 64];  // bf16, swizzled
  const int d = (dirSel >= 0) ? dirSel : (int)blockIdx.y;
  const int b0 = blockIdx.x * 16;
  const float* xg = d ? xgB : xgF;
  const float* Whh = d ? WhhB : WhhF;
  const int tid = threadIdx.x;
  const int w = tid >> 6;
  const int lane = tid & 63;
  const int cl = lane & 15;
  const int lq = lane >> 4;
  const int kk = 16 * w + cl;  // this lane's unit
  // --- stage W (bf16, slot swizzled by row&7) ---
  {
    const float* wr = Whh + (size_t)tid * 64;
#pragma unroll
    for (int s = 0; s < 8; ++s) {
      const float4 f0 = *(const float4*)(wr + 8 * s);
      const float4 f1 = *(const float4*)(wr + 8 * s + 4);
      const uint4 v = make_uint4(pk2bf(f0.x, f0.y), pk2bf(f0.z, f0.w),
                                 pk2bf(f1.x, f1.y), pk2bf(f1.z, f1.w));
      *(uint4*)&wS[tid * 64 + (s ^ (tid & 7)) * 8] = v;
    }
  }
  // --- c init (regs) + h0 stage into hS[0] ---
  float c[4];
#pragma unroll
  for (int j = 0; j < 4; ++j) {
    const int b = 4 * lq + j;
    c[j] = c0[(size_t)d * (Bn * 64) + (size_t)(b0 + b) * 64 + kk];
    const float hv = h0[(size_t)d * (Bn * 64) + (size_t)(b0 + b) * 64 + kk];
    hS[0][b * 64 + (((kk >> 3) ^ (b & 7)) * 8) + (kk & 7)] = f2bf(hv);
  }
  __syncthreads();
  // --- hoist W B-frags: tile a (gate type), chunk ch ---
  bf16x8 bf00, bf01, bf10, bf11, bf20, bf21, bf30, bf31;
  {
#define LDB(A, CH) \
    (*(const bf16x8*)&wS[(16 * (4 * (A) + w) + cl) * 64 + (((4 * (CH) + lq) ^ (cl & 7)) * 8)])
    bf00 = LDB(0, 0); bf01 = LDB(0, 1);
    bf10 = LDB(1, 0); bf11 = LDB(1, 1);
    bf20 = LDB(2, 0); bf21 = LDB(2, 1);
    bf30 = LDB(3, 0); bf31 = LDB(3, 1);
#undef LDB
  }
  const int t0 = d ? (Tn - 1) : 0;
  const int ts = d ? -1 : 1;
  float* fbase = feats + (size_t)b0 * Tn * Hn + (size_t)d * 64 + kk;
  float pA[4][4], pB[4][4];

#define LOADXG(P, T) do {                                                      \
    _Pragma("unroll")                                                          \
    for (int a_ = 0; a_ < 4; ++a_) {                                           \
      _Pragma("unroll")                                                        \
      for (int j_ = 0; j_ < 4; ++j_) {                                         \
        P[a_][j_] = xg[((size_t)(b0 + 4 * lq + j_) * Tn + (size_t)(T)) * G4    \
                       + 16 * (4 * a_ + w) + cl];                              \
      }                                                                        \
    }                                                                          \
  } while (0)

#define MF(AF, BF, ACC) \
    ACC = __builtin_amdgcn_mfma_f32_16x16x32_bf16(AF, BF, ACC, 0, 0, 0)

#define LSTM_STEP(PC, PN, T, RB, PF, TN) do {                                  \
    wg_barrier();                                                              \
    const bf16x8 af0 = *(const bf16x8*)&hS[RB][cl * 64 + ((lq ^ (cl & 7)) * 8)];      \
    const bf16x8 af1 = *(const bf16x8*)&hS[RB][cl * 64 + (((4 + lq) ^ (cl & 7)) * 8)];\
    if (PF) LOADXG(PN, TN);                                                    \
    f32x4 ac0 = {}, ac1 = {}, ac2 = {}, ac3 = {};                              \
    MF(af0, bf00, ac0); MF(af1, bf01, ac0);                                    \
    MF(af0, bf10, ac1); MF(af1, bf11, ac1);                                    \
    MF(af0, bf20, ac2); MF(af1, bf21, ac2);                                    \
    MF(af0, bf30, ac3); MF(af1, bf31, ac3);                                    \
    _Pragma("unroll")                                                          \
    for (int j = 0; j < 4; ++j) {                                              \
      const float ii = fast_sigm(ac0[j] + PC[0][j]);                           \
      const float ff = fast_sigm(ac1[j] + PC[1][j]);                           \
      const float gg = fast_tanh(ac2[j] + PC[2][j]);                           \
      const float oo = fast_sigm(ac3[j] + PC[3][j]);                           \
      c[j] = fmaf(ff, c[j], ii * gg);                                          \
      const float hh = oo * fast_tanh(c[j]);                                   \
      const int bb = 4 * lq + j;                                               \
      fbase[(size_t)bb * Tn * Hn + (size_t)(T) * Hn] = hh;                     \
      hS[(RB) ^ 1][bb * 64 + (((kk >> 3) ^ (bb & 7)) * 8) + (kk & 7)] = f2bf(hh); \
    }                                                                          \
  } while (0)

  LOADXG(pA, t0);
  for (int s = 0; s < Tn; s += 2) {
    const int tA = t0 + s * ts;
    const int tB = tA + ts;
    LSTM_STEP(pA, pB, tA, 0, 1, tB);
    LSTM_STEP(pB, pA, tB, 1, (s + 2 < Tn), tB + ts);
  }
#undef LSTM_STEP
#undef MF
#undef LOADXG
}

// ---------------- K3: emissions = feats @ W_out^T + b_out ----------------
__global__ __launch_bounds__(256) void emis_kernel(
    const float* __restrict__ feats, const float* __restrict__ Wout,
    const float* __restrict__ bout, float* __restrict__ em) {
  __shared__ __align__(16) float Wo[Kn * Hn];
  __shared__ float bo[Kn];
  const int tid = threadIdx.x;
  for (int i = tid; i < Kn * Hn; i += 256) Wo[i] = Wout[i];
  if (tid < Kn) bo[tid] = bout[tid];
  __syncthreads();
  const int n = blockIdx.x * 256 + tid;
  float acc[Kn];
#pragma unroll
  for (int k = 0; k < Kn; ++k) acc[k] = bo[k];
  const float4* fp = (const float4*)(feats + (size_t)n * Hn);
#pragma unroll 4
  for (int d4 = 0; d4 < 32; ++d4) {
    const float4 v = fp[d4];
#pragma unroll
    for (int k = 0; k < Kn; ++k) {
      const float4 w = *(const float4*)&Wo[k * Hn + d4 * 4];
      acc[k] = fmaf(v.x, w.x, acc[k]);
      acc[k] = fmaf(v.y, w.y, acc[k]);
      acc[k] = fmaf(v.z, w.z, acc[k]);
      acc[k] = fmaf(v.w, w.w, acc[k]);
    }
  }
  float* ep = em + (size_t)n * Kn;
#pragma unroll
  for (int k = 0; k < Kn; k += 4)
    *(float4*)&ep[k] = make_float4(acc[k], acc[k + 1], acc[k + 2], acc[k + 3]);
}

// ---------------- K4: Viterbi (one wave per sentence) ----------------
#define AMAX(v, a, v2, a2) { if ((v2) > (v)) { (v) = (v2); (a) = (a2); } }

__global__ __launch_bounds__(64) void viterbi_kernel(
    const float* __restrict__ em, const float* __restrict__ trans,
    float* __restrict__ out) {
  __shared__ __align__(16) float em_s[Tn * Kn];
  __shared__ float trans_s[Kn * Kn];
  __shared__ unsigned char bp[(Tn - 1) * Kn];
  __shared__ short path_s[Tn];
  const int tid = threadIdx.x;
  const int b = blockIdx.x;
  {
    const float4* ebv = (const float4*)(em + (size_t)b * Tn * Kn);
    float4* emv = (float4*)em_s;
    for (int i = tid; i < (Tn * Kn) / 4; i += 64) emv[i] = ebv[i];
  }
  for (int i = tid; i < Kn * Kn; i += 64) trans_s[i] = trans[i];
  __syncthreads();
  const int lane = (tid < Kn) ? tid : 0;
  float treg[Kn];
#pragma unroll
  for (int f = 0; f < Kn; ++f) treg[f] = trans_s[f * Kn + lane];
  float prev = em_s[lane];
  for (int t = 1; t < Tn; ++t) {
    float cv[Kn];
#pragma unroll
    for (int f = 0; f < Kn; ++f) cv[f] = __shfl(prev, f) + treg[f];
    float m0 = cv[0], m1 = cv[2], m2 = cv[4], m3 = cv[6], m4 = cv[8], m5 = cv[10];
    int a0 = 0, a1 = 2, a2 = 4, a3 = 6, a4 = 8, a5 = 10;
    AMAX(m0, a0, cv[1], 1);  AMAX(m1, a1, cv[3], 3);
    AMAX(m2, a2, cv[5], 5);  AMAX(m3, a3, cv[7], 7);
    AMAX(m4, a4, cv[9], 9);  AMAX(m5, a5, cv[11], 11);
    AMAX(m0, a0, m1, a1); AMAX(m2, a2, m3, a3); AMAX(m4, a4, m5, a5);
    AMAX(m0, a0, m2, a2); AMAX(m0, a0, m4, a4);
    prev = em_s[t * Kn + lane] + m0;
    if (tid < Kn) bp[(t - 1) * Kn + tid] = (unsigned char)a0;
  }
  float fv[Kn];
#pragma unroll
  for (int f = 0; f < Kn; ++f) fv[f] = __shfl(prev, f);
  float m0 = fv[0], m1 = fv[2], m2 = fv[4], m3 = fv[6], m4 = fv[8], m5 = fv[10];
  int a0 = 0, a1 = 2, a2 = 4, a3 = 6, a4 = 8, a5 = 10;
  AMAX(m0, a0, fv[1], 1);  AMAX(m1, a1, fv[3], 3);
  AMAX(m2, a2, fv[5], 5);  AMAX(m3, a3, fv[7], 7);
  AMAX(m4, a4, fv[9], 9);  AMAX(m5, a5, fv[11], 11);
  AMAX(m0, a0, m1, a1); AMAX(m2, a2, m3, a3); AMAX(m4, a4, m5, a5);
  AMAX(m0, a0, m2, a2); AMAX(m0, a0, m4, a4);
  __syncthreads();
  if (tid == 0) {
    out[b] = m0;
    int cur = a0;
    for (int i = Tn - 2; i >= 0; --i) {
      path_s[i + 1] = (short)cur;
      cur = bp[i * Kn + cur];
    }
    path_s[0] = (short)cur;
  }
  __syncthreads();
  for (int i = tid; i < Tn; i += 64)
    out[Bn + (size_t)b * Tn + i] = (float)path_s[i];
}

extern "C" void kernel_launch(void* const* d_in, const int* in_sizes, int n_in,
                              void* d_out, int out_size, void* d_ws, size_t ws_size,
                              hipStream_t stream) {
  const int*   sent  = (const int*)d_in[0];
  const float* embed = (const float*)d_in[1];
  const float* Wih_f = (const float*)d_in[2];
  const float* Whh_f = (const float*)d_in[3];
  const float* bih_f = (const float*)d_in[4];
  const float* bhh_f = (const float*)d_in[5];
  const float* Wih_b = (const float*)d_in[6];
  const float* Whh_b = (const float*)d_in[7];
  const float* bih_b = (const float*)d_in[8];
  const float* bhh_b = (const float*)d_in[9];
  const float* Wout  = (const float*)d_in[10];
  const float* bout  = (const float*)d_in[11];
  const float* trans = (const float*)d_in[12];
  const float* h0    = (const float*)d_in[13];
  const float* c0    = (const float*)d_in[14];
  float* out = (float*)d_out;

  char* ws = (char*)d_ws;
  const size_t xgBytes   = (size_t)Bn * Tn * G4 * sizeof(float);  // 64 MiB
  const size_t featBytes = (size_t)Bn * Tn * Hn * sizeof(float);  // 32 MiB
  const size_t emBytes   = (size_t)Bn * Tn * Kn * sizeof(float);  //  3 MiB
  const int tokBlocks = (Bn * Tn) / 64;  // 1024

  if (ws_size >= 2 * xgBytes + featBytes + emBytes) {
    float* xgF   = (float*)ws;
    float* xgB   = (float*)(ws + xgBytes);
    float* feats = (float*)(ws + 2 * xgBytes);
    float* emis  = (float*)(ws + 2 * xgBytes + featBytes);
    proj_kernel<<<dim3(tokBlocks, 2, 2), 256, 0, stream>>>(
        sent, embed, Wih_f, Wih_b, bih_f, bhh_f, bih_b, bhh_b, xgF, xgB, -1);
    lstm_mfma_kernel<<<dim3(8, 2), 256, 0, stream>>>(
        xgF, xgB, Whh_f, Whh_b, h0, c0, feats, -1);
    emis_kernel<<<256, 256, 0, stream>>>(feats, Wout, bout, emis);
    viterbi_kernel<<<128, 64, 0, stream>>>(emis, trans, out);
  } else {
    float* xgS   = (float*)ws;
    float* feats = (float*)(ws + xgBytes);
    float* emis  = (float*)(ws + xgBytes + featBytes);
    proj_kernel<<<dim3(tokBlocks, 2, 1), 256, 0, stream>>>(
        sent, embed, Wih_f, Wih_b, bih_f, bhh_f, bih_b, bhh_b, xgS, xgS, 0);
    lstm_mfma_kernel<<<dim3(8, 1), 256, 0, stream>>>(
        xgS, xgS, Whh_f, Whh_f, h0, c0, feats, 0);
    proj_kernel<<<dim3(tokBlocks, 2, 1), 256, 0, stream>>>(
        sent, embed, Wih_f, Wih_b, bih_f, bhh_f, bih_b, bhh_b, xgS, xgS, 1);
    lstm_mfma_kernel<<<dim3(8, 1), 256, 0, stream>>>(
        xgS, xgS, Whh_b, Whh_b, h0, c0, feats, 1);
    emis_kernel<<<256, 256, 0, stream>>>(feats, Wout, bout, emis);
    viterbi_kernel<<<128, 64, 0, stream>>>(emis, trans, out);
  }
}

// Round 14
// 447.453 us; speedup vs baseline: 1.1934x; 1.1934x over previous
//
#include <hip/hip_runtime.h>
#include <hip/hip_bf16.h>

#define Bn 128
#define Tn 512
#define En 100
#define G4 256   // 4*HD
#define Hn 128
#define Kn 12

typedef short bf16x8 __attribute__((ext_vector_type(8)));
typedef float f32x4 __attribute__((ext_vector_type(4)));
// exact type the AMDGCN packed-half builtins use
using h2_t = decltype(__builtin_amdgcn_cvt_pkrtz(0.0f, 0.0f));
union U32H2 { unsigned int u; float f; h2_t h; };

__device__ __forceinline__ float exp2_hw(float x) {
  float r; asm("v_exp_f32 %0, %1" : "=v"(r) : "v"(x)); return r;
}
__device__ __forceinline__ float rcp_hw(float x) {
  float r; asm("v_rcp_f32 %0, %1" : "=v"(r) : "v"(x)); return r;
}
__device__ __forceinline__ float fast_sigm(float x) {
  return rcp_hw(1.0f + exp2_hw(x * -1.4426950408889634f));
}
__device__ __forceinline__ float fast_tanh(float x) {
  return 1.0f - 2.0f * rcp_hw(1.0f + exp2_hw(x * 2.8853900817779268f));
}
__device__ __forceinline__ float fdot2(h2_t a, h2_t b, float c) {
#if __has_builtin(__builtin_amdgcn_fdot2)
  return __builtin_amdgcn_fdot2(a, b, c, false);
#else
  float r;
  asm("v_dot2_f32_f16 %0, %1, %2, %3" : "=v"(r) : "v"(a), "v"(b), "v"(c));
  return r;
#endif
}
// pack 2 floats -> 2 bf16 (RNE) in one u32
__device__ __forceinline__ unsigned int pk2bf(float a, float b) {
  unsigned int ua = __float_as_uint(a); ua += 0x7FFFu + ((ua >> 16) & 1u);
  unsigned int ub = __float_as_uint(b); ub += 0x7FFFu + ((ub >> 16) & 1u);
  return (ua >> 16) | (ub & 0xFFFF0000u);
}

// ---------------- K1: proj via MFMA bf16 (validated r10) ------------------
__global__ __launch_bounds__(256) void proj_kernel(
    const int* __restrict__ sent, const float* __restrict__ embed,
    const float* __restrict__ WihF, const float* __restrict__ WihB,
    const float* __restrict__ bihF, const float* __restrict__ bhhF,
    const float* __restrict__ bihB, const float* __restrict__ bhhB,
    float* __restrict__ xgF, float* __restrict__ xgB, int dirSel) {
  __shared__ __align__(16) unsigned short embS[64][128];
  __shared__ __align__(16) unsigned short wS[128][128];
  __shared__ float bias_s[128];
  const int tid = threadIdx.x;
  const int nhalf = blockIdx.y;
  const int dir = (dirSel >= 0) ? dirSel : (int)blockIdx.z;
  const float* Wih = dir ? WihB : WihF;
  const float* bih = dir ? bihB : bihF;
  const float* bhh = dir ? bhhB : bhhF;
  float* xg = dir ? xgB : xgF;
  const int n0 = blockIdx.x * 64;
  const int g0 = nhalf * 128;
  {
    const int t = tid >> 2, q = tid & 3;
    const int row = sent[n0 + t];
    const float* er = embed + (size_t)row * En;
    for (int c = q; c < 16; c += 4) {
      uint4 wv;
      if (c < 12) {
        const float4 f0 = *(const float4*)(er + 8 * c);
        const float4 f1 = *(const float4*)(er + 8 * c + 4);
        wv = make_uint4(pk2bf(f0.x, f0.y), pk2bf(f0.z, f0.w),
                        pk2bf(f1.x, f1.y), pk2bf(f1.z, f1.w));
      } else if (c == 12) {
        float f[8];
#pragma unroll
        for (int j = 0; j < 8; ++j) { const int e = 96 + j; f[j] = (e < En) ? er[e] : 0.f; }
        wv = make_uint4(pk2bf(f[0], f[1]), pk2bf(f[2], f[3]),
                        pk2bf(f[4], f[5]), pk2bf(f[6], f[7]));
      } else {
        wv = make_uint4(0, 0, 0, 0);
      }
      *(uint4*)&embS[t][8 * (c ^ (t & 7))] = wv;
    }
  }
  {
    const int r = tid >> 1, q = tid & 1;
    const float* wr = Wih + (size_t)(g0 + r) * En;
    for (int c = q; c < 16; c += 2) {
      uint4 wv;
      if (c < 12) {
        const float4 f0 = *(const float4*)(wr + 8 * c);
        const float4 f1 = *(const float4*)(wr + 8 * c + 4);
        wv = make_uint4(pk2bf(f0.x, f0.y), pk2bf(f0.z, f0.w),
                        pk2bf(f1.x, f1.y), pk2bf(f1.z, f1.w));
      } else if (c == 12) {
        float f[8];
#pragma unroll
        for (int j = 0; j < 8; ++j) { const int e = 96 + j; f[j] = (e < En) ? wr[e] : 0.f; }
        wv = make_uint4(pk2bf(f[0], f[1]), pk2bf(f[2], f[3]),
                        pk2bf(f[4], f[5]), pk2bf(f[6], f[7]));
      } else {
        wv = make_uint4(0, 0, 0, 0);
      }
      *(uint4*)&wS[r][8 * (c ^ (r & 7))] = wv;
    }
  }
  if (tid < 128) bias_s[tid] = bih[g0 + tid] + bhh[g0 + tid];
  __syncthreads();
  const int m = tid >> 6;
  const int lane = tid & 63;
  const int lr = lane & 15;
  const int lq = lane >> 4;
  const int t = 16 * m + lr;
  f32x4 acc[8] = {};
#pragma unroll
  for (int ks = 0; ks < 4; ++ks) {
    const int cs = 4 * ks + lq;
    const bf16x8 af = *(const bf16x8*)&embS[t][8 * (cs ^ (lr & 7))];
#pragma unroll
    for (int nt = 0; nt < 8; ++nt) {
      const int g = 16 * nt + lr;
      const bf16x8 bf = *(const bf16x8*)&wS[g][8 * (cs ^ (lr & 7))];
      acc[nt] = __builtin_amdgcn_mfma_f32_16x16x32_bf16(af, bf, acc[nt], 0, 0, 0);
    }
  }
  float* xbase = xg + (size_t)(n0 + 16 * m) * G4 + g0;
#pragma unroll
  for (int nt = 0; nt < 8; ++nt) {
    const int g = 16 * nt + lr;
    const float bv = bias_s[g];
#pragma unroll
    for (int j = 0; j < 4; ++j) {
      const int tok = 4 * lq + j;
      xbase[(size_t)tok * G4 + g] = acc[nt][j] + bv;
    }
  }
}

// ---------------- K2: LSTM recurrence, ZERO-SYNC single wave --------------
// One wave per (dir,batch). Lane l owns unit l: gate rows l, 64+l, 128+l,
// 192+l are ALL computed by lane l, so the c/h update is lane-local — no
// gate exchange, no LDS, no barrier. The only cross-lane op is the h
// all-gather, done in-register: shfl_xor(1)+cvt_pkrtz pack, then 32
// literal-lane broadcasts (depth-1). Weights pre-packed f16 (r12-proven
// numerics) live in 128 VGPRs (launch_bounds(64,1): 512-reg cap, no spill
// pressure; all arrays statically indexed per rule #20). Dot = 128
// v_dot2_f32_f16. Chain/step ~ shfl + 32-deep dot2 + act ~ 250-400 cyc
// vs the 1150-cyc barrier+LDS floor of r8-r12.
__global__ __launch_bounds__(64, 1) void lstm_kernel(
    const float* __restrict__ xgF, const float* __restrict__ xgB,
    const float* __restrict__ WhhF, const float* __restrict__ WhhB,
    const float* __restrict__ h0, const float* __restrict__ c0,
    float* __restrict__ feats, int dirSel) {
  int d, b;
  if (dirSel < 0) { d = blockIdx.x >> 7; b = blockIdx.x & 127; }
  else            { d = dirSel;          b = blockIdx.x; }
  const int lane = threadIdx.x & 63;
  const float* xg = d ? xgB : xgF;
  const float* Whh = d ? WhhB : WhhF;
  // --- pack W rows (i,f,g,o) of unit `lane` to f16 pairs, VGPR-resident ---
  unsigned int wpk[4][32];
#pragma unroll
  for (int r = 0; r < 4; ++r) {
    const float* wr = Whh + (size_t)(r * 64 + lane) * 64;
#pragma unroll
    for (int m = 0; m < 16; ++m) {
      const float4 q = *(const float4*)(wr + 4 * m);
      U32H2 pa, pb;
      pa.h = __builtin_amdgcn_cvt_pkrtz(q.x, q.y);
      pb.h = __builtin_amdgcn_cvt_pkrtz(q.z, q.w);
      wpk[r][2 * m] = pa.u;
      wpk[r][2 * m + 1] = pb.u;
    }
  }
  float c = c0[(size_t)d * (Bn * 64) + (size_t)b * 64 + lane];
  float h = h0[(size_t)d * (Bn * 64) + (size_t)b * 64 + lane];
  const float* xb = xg + (size_t)b * Tn * G4 + lane;
  float* fbase = feats + (size_t)b * Tn * Hn + d * 64 + lane;
  const int t0 = d ? (Tn - 1) : 0;
  const int ts = d ? -1 : 1;
  float pc0, pc1, pc2, pc3, pn0, pn1, pn2, pn3;
  {
    const float* xp = xb + (size_t)t0 * G4;
    pc0 = xp[0]; pc1 = xp[64]; pc2 = xp[128]; pc3 = xp[192];
  }

#define LSTM_STEP(X0, X1, X2, X3, N0, N1, N2, N3, T, PF, TN) do {              \
    /* in-register h all-gather as packed f16 */                               \
    const float hn_ = __shfl_xor(h, 1);                                        \
    U32H2 pp_;                                                                 \
    pp_.h = (lane & 1) ? __builtin_amdgcn_cvt_pkrtz(hn_, h)                    \
                       : __builtin_amdgcn_cvt_pkrtz(h, hn_);                   \
    const int p_ = (int)pp_.u;                                                 \
    unsigned int u_[32];                                                       \
    _Pragma("unroll")                                                          \
    for (int m = 0; m < 32; ++m) u_[m] = (unsigned int)__shfl(p_, 2 * m);      \
    if (PF) {                                                                  \
      const float* xp_ = xb + (size_t)(TN) * G4;                               \
      N0 = xp_[0]; N1 = xp_[64]; N2 = xp_[128]; N3 = xp_[192];                 \
    }                                                                          \
    float s0 = 0.f, s1 = 0.f, s2 = 0.f, s3 = 0.f;                              \
    _Pragma("unroll")                                                          \
    for (int m = 0; m < 32; ++m) {                                             \
      const h2_t hm_ = __builtin_bit_cast(h2_t, u_[m]);                        \
      s0 = fdot2(hm_, __builtin_bit_cast(h2_t, wpk[0][m]), s0);                \
      s1 = fdot2(hm_, __builtin_bit_cast(h2_t, wpk[1][m]), s1);                \
      s2 = fdot2(hm_, __builtin_bit_cast(h2_t, wpk[2][m]), s2);                \
      s3 = fdot2(hm_, __builtin_bit_cast(h2_t, wpk[3][m]), s3);                \
    }                                                                          \
    const float ii = fast_sigm(s0 + (X0));                                     \
    const float ff = fast_sigm(s1 + (X1));                                     \
    const float gg = fast_tanh(s2 + (X2));                                     \
    const float oo = fast_sigm(s3 + (X3));                                     \
    c = fmaf(ff, c, ii * gg);                                                  \
    h = oo * fast_tanh(c);                                                     \
    fbase[(size_t)(T) * Hn] = h;                                               \
  } while (0)

  for (int s = 0; s < Tn; s += 2) {
    const int tA = t0 + s * ts;
    const int tB = tA + ts;
    LSTM_STEP(pc0, pc1, pc2, pc3, pn0, pn1, pn2, pn3, tA, 1, tB);
    LSTM_STEP(pn0, pn1, pn2, pn3, pc0, pc1, pc2, pc3, tB, (s + 2 < Tn), tB + ts);
  }
#undef LSTM_STEP
}

// ---------------- K3: emissions = feats @ W_out^T + b_out ----------------
__global__ __launch_bounds__(256) void emis_kernel(
    const float* __restrict__ feats, const float* __restrict__ Wout,
    const float* __restrict__ bout, float* __restrict__ em) {
  __shared__ __align__(16) float Wo[Kn * Hn];
  __shared__ float bo[Kn];
  const int tid = threadIdx.x;
  for (int i = tid; i < Kn * Hn; i += 256) Wo[i] = Wout[i];
  if (tid < Kn) bo[tid] = bout[tid];
  __syncthreads();
  const int n = blockIdx.x * 256 + tid;
  float acc[Kn];
#pragma unroll
  for (int k = 0; k < Kn; ++k) acc[k] = bo[k];
  const float4* fp = (const float4*)(feats + (size_t)n * Hn);
#pragma unroll 4
  for (int d4 = 0; d4 < 32; ++d4) {
    const float4 v = fp[d4];
#pragma unroll
    for (int k = 0; k < Kn; ++k) {
      const float4 w = *(const float4*)&Wo[k * Hn + d4 * 4];
      acc[k] = fmaf(v.x, w.x, acc[k]);
      acc[k] = fmaf(v.y, w.y, acc[k]);
      acc[k] = fmaf(v.z, w.z, acc[k]);
      acc[k] = fmaf(v.w, w.w, acc[k]);
    }
  }
  float* ep = em + (size_t)n * Kn;
#pragma unroll
  for (int k = 0; k < Kn; k += 4)
    *(float4*)&ep[k] = make_float4(acc[k], acc[k + 1], acc[k + 2], acc[k + 3]);
}

// ---------------- K4: Viterbi (one wave per sentence) ----------------
#define AMAX(v, a, v2, a2) { if ((v2) > (v)) { (v) = (v2); (a) = (a2); } }

__global__ __launch_bounds__(64) void viterbi_kernel(
    const float* __restrict__ em, const float* __restrict__ trans,
    float* __restrict__ out) {
  __shared__ __align__(16) float em_s[Tn * Kn];
  __shared__ float trans_s[Kn * Kn];
  __shared__ unsigned char bp[(Tn - 1) * Kn];
  __shared__ short path_s[Tn];
  const int tid = threadIdx.x;
  const int b = blockIdx.x;
  {
    const float4* ebv = (const float4*)(em + (size_t)b * Tn * Kn);
    float4* emv = (float4*)em_s;
    for (int i = tid; i < (Tn * Kn) / 4; i += 64) emv[i] = ebv[i];
  }
  for (int i = tid; i < Kn * Kn; i += 64) trans_s[i] = trans[i];
  __syncthreads();
  const int lane = (tid < Kn) ? tid : 0;
  float treg[Kn];
#pragma unroll
  for (int f = 0; f < Kn; ++f) treg[f] = trans_s[f * Kn + lane];
  float prev = em_s[lane];
  for (int t = 1; t < Tn; ++t) {
    float cv[Kn];
#pragma unroll
    for (int f = 0; f < Kn; ++f) cv[f] = __shfl(prev, f) + treg[f];
    float m0 = cv[0], m1 = cv[2], m2 = cv[4], m3 = cv[6], m4 = cv[8], m5 = cv[10];
    int a0 = 0, a1 = 2, a2 = 4, a3 = 6, a4 = 8, a5 = 10;
    AMAX(m0, a0, cv[1], 1);  AMAX(m1, a1, cv[3], 3);
    AMAX(m2, a2, cv[5], 5);  AMAX(m3, a3, cv[7], 7);
    AMAX(m4, a4, cv[9], 9);  AMAX(m5, a5, cv[11], 11);
    AMAX(m0, a0, m1, a1); AMAX(m2, a2, m3, a3); AMAX(m4, a4, m5, a5);
    AMAX(m0, a0, m2, a2); AMAX(m0, a0, m4, a4);
    prev = em_s[t * Kn + lane] + m0;
    if (tid < Kn) bp[(t - 1) * Kn + tid] = (unsigned char)a0;
  }
  float fv[Kn];
#pragma unroll
  for (int f = 0; f < Kn; ++f) fv[f] = __shfl(prev, f);
  float m0 = fv[0], m1 = fv[2], m2 = fv[4], m3 = fv[6], m4 = fv[8], m5 = fv[10];
  int a0 = 0, a1 = 2, a2 = 4, a3 = 6, a4 = 8, a5 = 10;
  AMAX(m0, a0, fv[1], 1);  AMAX(m1, a1, fv[3], 3);
  AMAX(m2, a2, fv[5], 5);  AMAX(m3, a3, fv[7], 7);
  AMAX(m4, a4, fv[9], 9);  AMAX(m5, a5, fv[11], 11);
  AMAX(m0, a0, m1, a1); AMAX(m2, a2, m3, a3); AMAX(m4, a4, m5, a5);
  AMAX(m0, a0, m2, a2); AMAX(m0, a0, m4, a4);
  __syncthreads();
  if (tid == 0) {
    out[b] = m0;
    int cur = a0;
    for (int i = Tn - 2; i >= 0; --i) {
      path_s[i + 1] = (short)cur;
      cur = bp[i * Kn + cur];
    }
    path_s[0] = (short)cur;
  }
  __syncthreads();
  for (int i = tid; i < Tn; i += 64)
    out[Bn + (size_t)b * Tn + i] = (float)path_s[i];
}

extern "C" void kernel_launch(void* const* d_in, const int* in_sizes, int n_in,
                              void* d_out, int out_size, void* d_ws, size_t ws_size,
                              hipStream_t stream) {
  const int*   sent  = (const int*)d_in[0];
  const float* embed = (const float*)d_in[1];
  const float* Wih_f = (const float*)d_in[2];
  const float* Whh_f = (const float*)d_in[3];
  const float* bih_f = (const float*)d_in[4];
  const float* bhh_f = (const float*)d_in[5];
  const float* Wih_b = (const float*)d_in[6];
  const float* Whh_b = (const float*)d_in[7];
  const float* bih_b = (const float*)d_in[8];
  const float* bhh_b = (const float*)d_in[9];
  const float* Wout  = (const float*)d_in[10];
  const float* bout  = (const float*)d_in[11];
  const float* trans = (const float*)d_in[12];
  const float* h0    = (const float*)d_in[13];
  const float* c0    = (const float*)d_in[14];
  float* out = (float*)d_out;

  char* ws = (char*)d_ws;
  const size_t xgBytes   = (size_t)Bn * Tn * G4 * sizeof(float);  // 64 MiB
  const size_t featBytes = (size_t)Bn * Tn * Hn * sizeof(float);  // 32 MiB
  const size_t emBytes   = (size_t)Bn * Tn * Kn * sizeof(float);  //  3 MiB
  const int tokBlocks = (Bn * Tn) / 64;  // 1024

  if (ws_size >= 2 * xgBytes + featBytes + emBytes) {
    float* xgF   = (float*)ws;
    float* xgB   = (float*)(ws + xgBytes);
    float* feats = (float*)(ws + 2 * xgBytes);
    float* emis  = (float*)(ws + 2 * xgBytes + featBytes);
    proj_kernel<<<dim3(tokBlocks, 2, 2), 256, 0, stream>>>(
        sent, embed, Wih_f, Wih_b, bih_f, bhh_f, bih_b, bhh_b, xgF, xgB, -1);
    lstm_kernel<<<256, 64, 0, stream>>>(xgF, xgB, Whh_f, Whh_b, h0, c0, feats, -1);
    emis_kernel<<<256, 256, 0, stream>>>(feats, Wout, bout, emis);
    viterbi_kernel<<<128, 64, 0, stream>>>(emis, trans, out);
  } else {
    float* xgS   = (float*)ws;
    float* feats = (float*)(ws + xgBytes);
    float* emis  = (float*)(ws + xgBytes + featBytes);
    proj_kernel<<<dim3(tokBlocks, 2, 1), 256, 0, stream>>>(
        sent, embed, Wih_f, Wih_b, bih_f, bhh_f, bih_b, bhh_b, xgS, xgS, 0);
    lstm_kernel<<<128, 64, 0, stream>>>(xgS, xgS, Whh_f, Whh_f, h0, c0, feats, 0);
    proj_kernel<<<dim3(tokBlocks, 2, 1), 256, 0, stream>>>(
        sent, embed, Wih_f, Wih_b, bih_f, bhh_f, bih_b, bhh_b, xgS, xgS, 1);
    lstm_kernel<<<128, 64, 0, stream>>>(xgS, xgS, Whh_b, Whh_b, h0, c0, feats, 1);
    emis_kernel<<<256, 256, 0, stream>>>(feats, Wout, bout, emis);
    viterbi_kernel<<<128, 64, 0, stream>>>(emis, trans, out);
  }
}